// Round 1
// baseline (55.734 us; speedup 1.0000x reference)
//
#include <hip/hip_runtime.h>

#define NB 2
#define NT 4
#define NN 4096
#define NBT (NB*NT)
#define TOTAL (NBT*NN)        // 32768 points per tensor
#define BIGF 1e10f
#define THRESHF 1e9f
#define NEGF (-1e10f)

// ws layout (bytes):
//   packedT : [0,              TOTAL*16)
//   packedP : [TOTAL*16,       TOTAL*32)
//   minp    : [TOTAL*32,       TOTAL*36)   (uint bits of float, all >= 0)
//   mint    : [TOTAL*36,       TOTAL*40)

__global__ __launch_bounds__(256) void prep_kernel(
    const float* __restrict__ pred, const float* __restrict__ targ,
    const int* __restrict__ ic, const int* __restrict__ pad, const int* __restrict__ vis,
    float4* __restrict__ packedP, float4* __restrict__ packedT,
    unsigned* __restrict__ minp, unsigned* __restrict__ mint,
    float* __restrict__ out)
{
    int i = blockIdx.x * 256 + threadIdx.x;
    if (i == 0) out[0] = 0.0f;              // zero output each call (poison-safe)
    if (i >= TOTAL) return;
    int bt = i >> 12;                        // /NN
    int n  = i & (NN - 1);
    int b  = bt >> 2;                        // /NT
    bool m = (ic[b*NN + n] == 0) && (pad[b*NN + n] != 0) && (vis[i] != 0);
    float bias = m ? 0.0f : BIGF;
    float px = pred[3*i], py = pred[3*i+1], pz = pred[3*i+2];
    float tx = targ[3*i], ty = targ[3*i+1], tz = targ[3*i+2];
    packedP[i] = make_float4(px, py, pz, fmaf(px,px, fmaf(py,py, pz*pz)) + bias);
    packedT[i] = make_float4(tx, ty, tz, fmaf(tx,tx, fmaf(ty,ty, tz*tz)) + bias);
    minp[i] = __float_as_uint(BIGF);
    mint[i] = __float_as_uint(BIGF);
}

#define COLS 512   // columns staged per block (8 KB LDS)
// grid: (colChunks=8, rowChunks=4, NBT*2=16), block=256; 4 rows/thread
__global__ __launch_bounds__(256) void min_kernel(
    const float4* __restrict__ packedP, const float4* __restrict__ packedT,
    unsigned* __restrict__ minp, unsigned* __restrict__ mint)
{
    __shared__ float4 cols[COLS];
    const int tid = threadIdx.x;
    const int cc  = blockIdx.x;
    const int rc  = blockIdx.y;
    const int z   = blockIdx.z;
    const int bt  = z >> 1;
    const int dir = z & 1;
    const float4* __restrict__ rowsPtr = dir ? packedT : packedP;
    const float4* __restrict__ colsPtr = dir ? packedP : packedT;
    unsigned* outp = dir ? mint : minp;
    const int base = bt * NN;

    cols[tid]       = colsPtr[base + cc*COLS + tid];
    cols[tid + 256] = colsPtr[base + cc*COLS + tid + 256];
    __syncthreads();

    const int r = base + rc*1024 + tid;
    float4 a0 = rowsPtr[r];
    float4 a1 = rowsPtr[r + 256];
    float4 a2 = rowsPtr[r + 512];
    float4 a3 = rowsPtr[r + 768];
    // recompute unbiased ||p||^2 for the row side
    a0.w = fmaf(a0.x,a0.x, fmaf(a0.y,a0.y, a0.z*a0.z));
    a1.w = fmaf(a1.x,a1.x, fmaf(a1.y,a1.y, a1.z*a1.z));
    a2.w = fmaf(a2.x,a2.x, fmaf(a2.y,a2.y, a2.z*a2.z));
    a3.w = fmaf(a3.x,a3.x, fmaf(a3.y,a3.y, a3.z*a3.z));

    float m0 = 3.4e38f, m1 = 3.4e38f, m2 = 3.4e38f, m3 = 3.4e38f;
    #pragma unroll 4
    for (int j = 0; j < COLS; ++j) {
        float4 t = cols[j];
        float d0 = fmaf(-2.0f, fmaf(a0.x,t.x, fmaf(a0.y,t.y, a0.z*t.z)), a0.w + t.w);
        float d1 = fmaf(-2.0f, fmaf(a1.x,t.x, fmaf(a1.y,t.y, a1.z*t.z)), a1.w + t.w);
        float d2 = fmaf(-2.0f, fmaf(a2.x,t.x, fmaf(a2.y,t.y, a2.z*t.z)), a2.w + t.w);
        float d3 = fmaf(-2.0f, fmaf(a3.x,t.x, fmaf(a3.y,t.y, a3.z*t.z)), a3.w + t.w);
        m0 = fminf(m0, d0);
        m1 = fminf(m1, d1);
        m2 = fminf(m2, d2);
        m3 = fminf(m3, d3);
    }
    // clamp after the min: min_m max(d,0) == max(min_m d, 0); keeps values >= 0 for uint atomicMin
    m0 = fmaxf(m0, 0.0f);
    m1 = fmaxf(m1, 0.0f);
    m2 = fmaxf(m2, 0.0f);
    m3 = fmaxf(m3, 0.0f);
    atomicMin(&outp[r],       __float_as_uint(m0));
    atomicMin(&outp[r + 256], __float_as_uint(m1));
    atomicMin(&outp[r + 512], __float_as_uint(m2));
    atomicMin(&outp[r + 768], __float_as_uint(m3));
}

// one block per (b,t): cd + soft-hausdorff, atomicAdd contribution into out[0]
__global__ __launch_bounds__(256) void finalize_kernel(
    const unsigned* __restrict__ minp, const unsigned* __restrict__ mint,
    const int* __restrict__ ic, const int* __restrict__ pad, const int* __restrict__ vis,
    float* __restrict__ out)
{
    const int bt = blockIdx.x;
    const int b  = bt >> 2;
    const int tid = threadIdx.x;

    float hp[16], ht[16];
    float nv = 0.f, scdp = 0.f, scdt = 0.f, mhp = NEGF, mht = NEGF;
    #pragma unroll
    for (int k = 0; k < 16; ++k) {
        int n  = tid + k*256;
        int gi = bt*NN + n;
        bool m = (ic[b*NN + n] == 0) && (pad[b*NN + n] != 0) && (vis[gi] != 0);
        float mp = __uint_as_float(minp[gi]);
        float mt = __uint_as_float(mint[gi]);
        float hpv = m ? fminf(mp, THRESHF) : NEGF;
        float htv = m ? fminf(mt, THRESHF) : NEGF;
        hp[k] = hpv; ht[k] = htv;
        if (m) {
            nv += 1.f;
            scdp += (mp > THRESHF) ? 0.f : mp;
            scdt += (mt > THRESHF) ? 0.f : mt;
            mhp = fmaxf(mhp, hpv);
            mht = fmaxf(mht, htv);
        }
    }

    __shared__ float red[4][5];
    const int wid = tid >> 6;
    #pragma unroll
    for (int o = 32; o > 0; o >>= 1) {
        nv   += __shfl_xor(nv, o);
        scdp += __shfl_xor(scdp, o);
        scdt += __shfl_xor(scdt, o);
        mhp   = fmaxf(mhp, __shfl_xor(mhp, o));
        mht   = fmaxf(mht, __shfl_xor(mht, o));
    }
    if ((tid & 63) == 0) {
        red[wid][0] = nv; red[wid][1] = scdp; red[wid][2] = scdt;
        red[wid][3] = mhp; red[wid][4] = mht;
    }
    __syncthreads();
    nv   = red[0][0] + red[1][0] + red[2][0] + red[3][0];
    scdp = red[0][1] + red[1][1] + red[2][1] + red[3][1];
    scdt = red[0][2] + red[1][2] + red[2][2] + red[3][2];
    mhp  = fmaxf(fmaxf(red[0][3], red[1][3]), fmaxf(red[2][3], red[3][3]));
    mht  = fmaxf(fmaxf(red[0][4], red[1][4]), fmaxf(red[2][4], red[3][4]));
    __syncthreads();

    float Zp = 0.f, Sp = 0.f, Zt = 0.f, St = 0.f;
    #pragma unroll
    for (int k = 0; k < 16; ++k) {
        float hpv = hp[k];
        if (hpv > -THRESHF) { float e = __expf((hpv - mhp) * 10.0f); Zp += e; Sp += hpv * e; }
        float htv = ht[k];
        if (htv > -THRESHF) { float e = __expf((htv - mht) * 10.0f); Zt += e; St += htv * e; }
    }
    #pragma unroll
    for (int o = 32; o > 0; o >>= 1) {
        Zp += __shfl_xor(Zp, o);
        Sp += __shfl_xor(Sp, o);
        Zt += __shfl_xor(Zt, o);
        St += __shfl_xor(St, o);
    }
    if ((tid & 63) == 0) {
        red[wid][0] = Zp; red[wid][1] = Sp; red[wid][2] = Zt; red[wid][3] = St;
    }
    __syncthreads();
    if (tid == 0) {
        Zp = red[0][0] + red[1][0] + red[2][0] + red[3][0];
        Sp = red[0][1] + red[1][1] + red[2][1] + red[3][1];
        Zt = red[0][2] + red[1][2] + red[2][2] + red[3][2];
        St = red[0][3] + red[1][3] + red[2][3] + red[3][3];
        float nvm = fmaxf(nv, 1.f);
        float cd  = scdp / nvm + scdt / nvm;
        float sp  = (nv > 0.f) ? (Sp / Zp) : 0.f;
        float st  = (nv > 0.f) ? (St / Zt) : 0.f;
        float hd  = fmaxf(sp, st);
        atomicAdd(out, (0.5f * cd + 0.5f * hd) * 0.125f);
    }
}

extern "C" void kernel_launch(void* const* d_in, const int* in_sizes, int n_in,
                              void* d_out, int out_size, void* d_ws, size_t ws_size,
                              hipStream_t stream)
{
    const float* pred = (const float*)d_in[0];
    const float* targ = (const float*)d_in[1];
    const int*   ic   = (const int*)d_in[2];
    const int*   pad  = (const int*)d_in[3];
    const int*   vis  = (const int*)d_in[4];
    float* out = (float*)d_out;

    char* ws = (char*)d_ws;
    float4*   packedT = (float4*)(ws);
    float4*   packedP = (float4*)(ws + (size_t)TOTAL * 16);
    unsigned* minp    = (unsigned*)(ws + (size_t)TOTAL * 32);
    unsigned* mint    = (unsigned*)(ws + (size_t)TOTAL * 32 + (size_t)TOTAL * 4);

    prep_kernel<<<TOTAL/256, 256, 0, stream>>>(pred, targ, ic, pad, vis,
                                               packedP, packedT, minp, mint, out);
    dim3 grid(NN/COLS, NN/1024, NBT*2);   // (8, 4, 16)
    min_kernel<<<grid, 256, 0, stream>>>(packedP, packedT, minp, mint);
    finalize_kernel<<<NBT, 256, 0, stream>>>(minp, mint, ic, pad, vis, out);
}

// Round 2
// 47.063 us; speedup vs baseline: 1.1842x; 1.1842x over previous
//
#include <hip/hip_runtime.h>

#define NB 2
#define NT 4
#define NN 4096
#define NBT (NB*NT)
#define TOTAL (NBT*NN)        // 32768 points per tensor
#define BIGF 1e10f
#define THRESHF 1e9f
#define NEGF (-1e10f)

// ws layout (bytes):
//   packedT : [0,              TOTAL*16)   (x,y,z, ||.||^2 + bias)
//   packedP : [TOTAL*16,       TOTAL*32)
//   minp    : [TOTAL*32,       TOTAL*36)   (uint bits of float, all >= 0)
//   mint    : [TOTAL*36,       TOTAL*40)

__global__ __launch_bounds__(256) void prep_kernel(
    const float* __restrict__ pred, const float* __restrict__ targ,
    const int* __restrict__ ic, const int* __restrict__ pad, const int* __restrict__ vis,
    float4* __restrict__ packedP, float4* __restrict__ packedT,
    unsigned* __restrict__ minp, unsigned* __restrict__ mint,
    float* __restrict__ out)
{
    int i = blockIdx.x * 256 + threadIdx.x;
    if (i == 0) out[0] = 0.0f;              // zero output each call (poison-safe)
    if (i >= TOTAL) return;
    int bt = i >> 12;                        // /NN
    int n  = i & (NN - 1);
    int b  = bt >> 2;                        // /NT
    bool m = (ic[b*NN + n] == 0) && (pad[b*NN + n] != 0) && (vis[i] != 0);
    float bias = m ? 0.0f : BIGF;
    float px = pred[3*i], py = pred[3*i+1], pz = pred[3*i+2];
    float tx = targ[3*i], ty = targ[3*i+1], tz = targ[3*i+2];
    packedP[i] = make_float4(px, py, pz, fmaf(px,px, fmaf(py,py, pz*pz)) + bias);
    packedT[i] = make_float4(tx, ty, tz, fmaf(tx,tx, fmaf(ty,ty, tz*tz)) + bias);
    minp[i] = __float_as_uint(BIGF);
    mint[i] = __float_as_uint(BIGF);
}

#define COLS 256   // columns staged per block (4 KB LDS)
#define RPT  8     // rows per thread
// grid: (colChunks=16, rowChunks=2, NBT*2=16), block=256
__global__ __launch_bounds__(256, 4) void min_kernel(
    const float4* __restrict__ packedP, const float4* __restrict__ packedT,
    unsigned* __restrict__ minp, unsigned* __restrict__ mint)
{
    __shared__ float4 cols[COLS];
    const int tid = threadIdx.x;
    const int cc  = blockIdx.x;
    const int rc  = blockIdx.y;
    const int z   = blockIdx.z;
    const int bt  = z >> 1;
    const int dir = z & 1;
    const float4* __restrict__ rowsPtr = dir ? packedT : packedP;
    const float4* __restrict__ colsPtr = dir ? packedP : packedT;
    unsigned* outp = dir ? mint : minp;
    const int base = bt * NN;

    // stage columns with -2 folded in; keep biased norm in .w
    float4 c = colsPtr[base + cc*COLS + tid];
    cols[tid] = make_float4(-2.0f*c.x, -2.0f*c.y, -2.0f*c.z, c.w);
    __syncthreads();

    const int r = base + rc*(256*RPT) + tid;
    float4 a[RPT];
    float  w[RPT];   // unbiased row norm, added after the min
    float  m[RPT];
    #pragma unroll
    for (int k = 0; k < RPT; ++k) {
        a[k] = rowsPtr[r + k*256];
        w[k] = fmaf(a[k].x,a[k].x, fmaf(a[k].y,a[k].y, a[k].z*a[k].z));
        m[k] = 3.4e38f;
    }

    #pragma unroll 4
    for (int j = 0; j < COLS; ++j) {
        float4 t = cols[j];
        #pragma unroll
        for (int k = 0; k < RPT; ++k) {
            float d = fmaf(a[k].x, t.x, fmaf(a[k].y, t.y, fmaf(a[k].z, t.z, t.w)));
            m[k] = fminf(m[k], d);
        }
    }

    // add row norm once, clamp at 0 (min/max commute), publish
    #pragma unroll
    for (int k = 0; k < RPT; ++k) {
        float v = fmaxf(m[k] + w[k], 0.0f);
        atomicMin(&outp[r + k*256], __float_as_uint(v));
    }
}

// one block per (b,t): cd + soft-hausdorff, atomicAdd contribution into out[0]
__global__ __launch_bounds__(256) void finalize_kernel(
    const unsigned* __restrict__ minp, const unsigned* __restrict__ mint,
    const int* __restrict__ ic, const int* __restrict__ pad, const int* __restrict__ vis,
    float* __restrict__ out)
{
    const int bt = blockIdx.x;
    const int b  = bt >> 2;
    const int tid = threadIdx.x;

    float hp[16], ht[16];
    float nv = 0.f, scdp = 0.f, scdt = 0.f, mhp = NEGF, mht = NEGF;
    #pragma unroll
    for (int k = 0; k < 16; ++k) {
        int n  = tid + k*256;
        int gi = bt*NN + n;
        bool m = (ic[b*NN + n] == 0) && (pad[b*NN + n] != 0) && (vis[gi] != 0);
        float mp = __uint_as_float(minp[gi]);
        float mt = __uint_as_float(mint[gi]);
        float hpv = m ? fminf(mp, THRESHF) : NEGF;
        float htv = m ? fminf(mt, THRESHF) : NEGF;
        hp[k] = hpv; ht[k] = htv;
        if (m) {
            nv += 1.f;
            scdp += (mp > THRESHF) ? 0.f : mp;
            scdt += (mt > THRESHF) ? 0.f : mt;
            mhp = fmaxf(mhp, hpv);
            mht = fmaxf(mht, htv);
        }
    }

    __shared__ float red[4][5];
    const int wid = tid >> 6;
    #pragma unroll
    for (int o = 32; o > 0; o >>= 1) {
        nv   += __shfl_xor(nv, o);
        scdp += __shfl_xor(scdp, o);
        scdt += __shfl_xor(scdt, o);
        mhp   = fmaxf(mhp, __shfl_xor(mhp, o));
        mht   = fmaxf(mht, __shfl_xor(mht, o));
    }
    if ((tid & 63) == 0) {
        red[wid][0] = nv; red[wid][1] = scdp; red[wid][2] = scdt;
        red[wid][3] = mhp; red[wid][4] = mht;
    }
    __syncthreads();
    nv   = red[0][0] + red[1][0] + red[2][0] + red[3][0];
    scdp = red[0][1] + red[1][1] + red[2][1] + red[3][1];
    scdt = red[0][2] + red[1][2] + red[2][2] + red[3][2];
    mhp  = fmaxf(fmaxf(red[0][3], red[1][3]), fmaxf(red[2][3], red[3][3]));
    mht  = fmaxf(fmaxf(red[0][4], red[1][4]), fmaxf(red[2][4], red[3][4]));
    __syncthreads();

    float Zp = 0.f, Sp = 0.f, Zt = 0.f, St = 0.f;
    #pragma unroll
    for (int k = 0; k < 16; ++k) {
        float hpv = hp[k];
        if (hpv > -THRESHF) { float e = __expf((hpv - mhp) * 10.0f); Zp += e; Sp += hpv * e; }
        float htv = ht[k];
        if (htv > -THRESHF) { float e = __expf((htv - mht) * 10.0f); Zt += e; St += htv * e; }
    }
    #pragma unroll
    for (int o = 32; o > 0; o >>= 1) {
        Zp += __shfl_xor(Zp, o);
        Sp += __shfl_xor(Sp, o);
        Zt += __shfl_xor(Zt, o);
        St += __shfl_xor(St, o);
    }
    if ((tid & 63) == 0) {
        red[wid][0] = Zp; red[wid][1] = Sp; red[wid][2] = Zt; red[wid][3] = St;
    }
    __syncthreads();
    if (tid == 0) {
        Zp = red[0][0] + red[1][0] + red[2][0] + red[3][0];
        Sp = red[0][1] + red[1][1] + red[2][1] + red[3][1];
        Zt = red[0][2] + red[1][2] + red[2][2] + red[3][2];
        St = red[0][3] + red[1][3] + red[2][3] + red[3][3];
        float nvm = fmaxf(nv, 1.f);
        float cd  = scdp / nvm + scdt / nvm;
        float sp  = (nv > 0.f) ? (Sp / Zp) : 0.f;
        float st  = (nv > 0.f) ? (St / Zt) : 0.f;
        float hd  = fmaxf(sp, st);
        atomicAdd(out, (0.5f * cd + 0.5f * hd) * 0.125f);
    }
}

extern "C" void kernel_launch(void* const* d_in, const int* in_sizes, int n_in,
                              void* d_out, int out_size, void* d_ws, size_t ws_size,
                              hipStream_t stream)
{
    const float* pred = (const float*)d_in[0];
    const float* targ = (const float*)d_in[1];
    const int*   ic   = (const int*)d_in[2];
    const int*   pad  = (const int*)d_in[3];
    const int*   vis  = (const int*)d_in[4];
    float* out = (float*)d_out;

    char* ws = (char*)d_ws;
    float4*   packedT = (float4*)(ws);
    float4*   packedP = (float4*)(ws + (size_t)TOTAL * 16);
    unsigned* minp    = (unsigned*)(ws + (size_t)TOTAL * 32);
    unsigned* mint    = (unsigned*)(ws + (size_t)TOTAL * 32 + (size_t)TOTAL * 4);

    prep_kernel<<<TOTAL/256, 256, 0, stream>>>(pred, targ, ic, pad, vis,
                                               packedP, packedT, minp, mint, out);
    dim3 grid(NN/COLS, NN/(256*RPT), NBT*2);   // (16, 2, 16)
    min_kernel<<<grid, 256, 0, stream>>>(packedP, packedT, minp, mint);
    finalize_kernel<<<NBT, 256, 0, stream>>>(minp, mint, ic, pad, vis, out);
}